// Round 1
// baseline (6222.454 us; speedup 1.0000x reference)
//
#include <hip/hip_runtime.h>
#include <math.h>

#define N_BATCH 256
#define L_SEQ   2048
#define QK_DIM  512
#define H_DIM   128

#define LT 64   // l-tile per block in energy kernel
#define DT 32   // k-chunk (d) per LDS stage

// ---------------------------------------------------------------------------
// q[n][h] = sum_d lh[n][d] * Wa[h][d]        (N x H = 256 x 128, tiny)
// one block per n, 128 threads (one per h)
// ---------------------------------------------------------------------------
__global__ __launch_bounds__(128) void qk_kernel(const float* __restrict__ lh,
                                                 const float* __restrict__ Wa,
                                                 float* __restrict__ qout) {
    int n = blockIdx.x;
    int h = threadIdx.x;
    __shared__ float s_lh[QK_DIM];
    // stage lh row: 128 threads x float4 = 512 floats
    ((float4*)s_lh)[h] = ((const float4*)(lh + (size_t)n * QK_DIM))[h];
    __syncthreads();
    const float4* wa4 = (const float4*)(Wa + (size_t)h * QK_DIM);
    const float4* s4  = (const float4*)s_lh;
    float acc = 0.f;
#pragma unroll 8
    for (int dq = 0; dq < QK_DIM / 4; ++dq) {
        float4 a = s4[dq];       // broadcast across threads
        float4 b = wa4[dq];
        acc += a.x * b.x + a.y * b.y + a.z * b.z + a.w * b.w;
    }
    qout[(size_t)n * H_DIM + h] = acc;
}

// ---------------------------------------------------------------------------
// energies[n][l] = sum_h va[h] * tanh(q[n][h] + sum_d enc[n][l][d]*Ua[h][d])
// grid (N, L/LT), block 128 threads (one per h). LDS-tiled over d.
// ---------------------------------------------------------------------------
__global__ __launch_bounds__(128) void energy_kernel(const float* __restrict__ enc,
                                                     const float* __restrict__ Ua,
                                                     const float* __restrict__ q,
                                                     const float* __restrict__ va,
                                                     float* __restrict__ energies) {
    const int n  = blockIdx.x;
    const int l0 = blockIdx.y * LT;
    const int h  = threadIdx.x;   // 0..127

    __shared__ float s_enc[LT][DT + 4];     // +4 keeps 16B row align, breaks pow2 stride
    __shared__ float s_ua[H_DIM][DT + 4];
    __shared__ float s_part[2][LT];

    float acc[LT];
#pragma unroll
    for (int i = 0; i < LT; ++i) acc[i] = 0.f;

    const float qh  = q[(size_t)n * H_DIM + h];
    const float vah = va[h];

    for (int d0 = 0; d0 < QK_DIM; d0 += DT) {
        // stage enc tile: LT x DT = 2048 floats, 128 thr -> 4 float4 each
#pragma unroll
        for (int i = 0; i < (LT * DT) / (128 * 4); ++i) {
            int idx = i * 128 + h;           // float4 index within tile
            int l   = idx / (DT / 4);
            int c   = idx % (DT / 4);
            float4 v = *(const float4*)(enc + ((size_t)n * L_SEQ + l0 + l) * QK_DIM + d0 + c * 4);
            *(float4*)(&s_enc[l][c * 4]) = v;
        }
        // stage Ua tile: H x DT = 4096 floats, 8 float4 each
#pragma unroll
        for (int i = 0; i < (H_DIM * DT) / (128 * 4); ++i) {
            int idx = i * 128 + h;
            int hh  = idx / (DT / 4);
            int c   = idx % (DT / 4);
            float4 v = *(const float4*)(Ua + (size_t)hh * QK_DIM + d0 + c * 4);
            *(float4*)(&s_ua[hh][c * 4]) = v;
        }
        __syncthreads();
#pragma unroll
        for (int dq = 0; dq < DT / 4; ++dq) {
            float4 u = *(const float4*)(&s_ua[h][dq * 4]);
#pragma unroll
            for (int l = 0; l < LT; ++l) {
                float4 e = *(const float4*)(&s_enc[l][dq * 4]);  // broadcast
                acc[l] += e.x * u.x + e.y * u.y + e.z * u.z + e.w * u.w;
            }
        }
        __syncthreads();
    }

    // acc[l] = k[n][l0+l][h]; reduce va[h]*tanh(qh+acc[l]) over h (128 threads)
    const int wave = h >> 6;
    const int lane = h & 63;
#pragma unroll
    for (int l = 0; l < LT; ++l) {
        float v = vah * tanhf(qh + acc[l]);
#pragma unroll
        for (int off = 32; off > 0; off >>= 1)
            v += __shfl_down(v, off, 64);
        if (lane == 0) s_part[wave][l] = v;
    }
    __syncthreads();
    if (h < LT)
        energies[(size_t)n * L_SEQ + l0 + h] = s_part[0][h] + s_part[1][h];
}

// ---------------------------------------------------------------------------
// in-place softmax over L per row n. one block (256 thr) per n, 8 elems/thread
// ---------------------------------------------------------------------------
__global__ __launch_bounds__(256) void softmax_kernel(float* __restrict__ w) {
    const int n   = blockIdx.x;
    const int tid = threadIdx.x;
    const int lane = tid & 63, wv = tid >> 6;
    __shared__ float s_m[4];
    __shared__ float s_s[4];

    float e[8];
    float m = -1e30f;
#pragma unroll
    for (int i = 0; i < 8; ++i) {
        e[i] = w[(size_t)n * L_SEQ + i * 256 + tid];
        m = fmaxf(m, e[i]);
    }
#pragma unroll
    for (int off = 32; off > 0; off >>= 1)
        m = fmaxf(m, __shfl_down(m, off, 64));
    if (lane == 0) s_m[wv] = m;
    __syncthreads();
    m = fmaxf(fmaxf(s_m[0], s_m[1]), fmaxf(s_m[2], s_m[3]));

    float sum = 0.f;
#pragma unroll
    for (int i = 0; i < 8; ++i) {
        e[i] = __expf(e[i] - m);
        sum += e[i];
    }
#pragma unroll
    for (int off = 32; off > 0; off >>= 1)
        sum += __shfl_down(sum, off, 64);
    if (lane == 0) s_s[wv] = sum;
    __syncthreads();
    sum = s_s[0] + s_s[1] + s_s[2] + s_s[3];
    const float inv = 1.0f / sum;
#pragma unroll
    for (int i = 0; i < 8; ++i)
        w[(size_t)n * L_SEQ + i * 256 + tid] = e[i] * inv;
}

// ---------------------------------------------------------------------------
__global__ void zero_kernel(float* __restrict__ p, int count) {
    int i = blockIdx.x * 256 + threadIdx.x;
    if (i < count) p[i] = 0.f;
}

// ---------------------------------------------------------------------------
// ctx[n][d] = sum_l w[n][l] * enc[n][l][d]
// grid (N, 2 d-halves, 4 l-quarters), 256 thr; atomic partial accumulation
// ---------------------------------------------------------------------------
__global__ __launch_bounds__(256) void context_kernel(const float* __restrict__ enc,
                                                      const float* __restrict__ w,
                                                      float* __restrict__ ctx) {
    const int n = blockIdx.x;
    const int d = blockIdx.y * 256 + threadIdx.x;
    const int lq = blockIdx.z;  // 0..3, 512 l each
    const float* ep = enc + ((size_t)n * L_SEQ + (size_t)lq * 512) * QK_DIM + d;
    const float* wp = w + (size_t)n * L_SEQ + (size_t)lq * 512;
    float acc = 0.f;
#pragma unroll 8
    for (int l = 0; l < 512; ++l)
        acc += wp[l] * ep[(size_t)l * QK_DIM];
    atomicAdd(&ctx[(size_t)n * QK_DIM + d], acc);
}

// ---------------------------------------------------------------------------
extern "C" void kernel_launch(void* const* d_in, const int* in_sizes, int n_in,
                              void* d_out, int out_size, void* d_ws, size_t ws_size,
                              hipStream_t stream) {
    const float* lh  = (const float*)d_in[0];
    const float* enc = (const float*)d_in[1];
    const float* Wa  = (const float*)d_in[2];
    const float* Ua  = (const float*)d_in[3];
    const float* va  = (const float*)d_in[4];

    float* ctx = (float*)d_out;                        // [256*512]
    float* wts = (float*)d_out + N_BATCH * QK_DIM;     // [256*2048]
    float* qbuf = ctx;  // q (32768 floats) parked in ctx region; consumed by
                        // energy_kernel, then ctx region is zeroed & rebuilt.

    qk_kernel<<<dim3(N_BATCH), dim3(128), 0, stream>>>(lh, Wa, qbuf);
    energy_kernel<<<dim3(N_BATCH, L_SEQ / LT), dim3(128), 0, stream>>>(enc, Ua, qbuf, va, wts);
    softmax_kernel<<<dim3(N_BATCH), dim3(256), 0, stream>>>(wts);
    zero_kernel<<<dim3((N_BATCH * QK_DIM) / 256), dim3(256), 0, stream>>>(ctx, N_BATCH * QK_DIM);
    context_kernel<<<dim3(N_BATCH, 2, 4), dim3(256), 0, stream>>>(enc, wts, ctx);
}